// Round 10
// baseline (98.561 us; speedup 1.0000x reference)
//
#include <hip/hip_runtime.h>
#include <hip/hip_bf16.h>

#define NN 8192
#define DD 128

typedef __attribute__((ext_vector_type(4))) float f32x4;
typedef __attribute__((ext_vector_type(16))) float f32x16;
typedef __attribute__((ext_vector_type(8))) short bf16x8;
typedef __attribute__((ext_vector_type(4))) short s16x4;

__device__ __forceinline__ short f2bf(float f) {
  __hip_bfloat16 h = __float2bfloat16(f);
  return __builtin_bit_cast(short, h);
}
__device__ __forceinline__ float bf2f(short s) {
  unsigned u = ((unsigned)(unsigned short)s) << 16;
  return __builtin_bit_cast(float, u);
}

__device__ __forceinline__ void async_copy16(void* lds, const void* g) {
  __builtin_amdgcn_global_load_lds(
      (const __attribute__((address_space(1))) void*)g,
      (__attribute__((address_space(3))) void*)lds, 16, 0, 0);
}

// ---------------------------------------------------------------------------
// Kernel 1: yT[n][k] = sum_d x[k][d] * W[d][n]   (bf16, transposed)
// ---------------------------------------------------------------------------
__global__ __launch_bounds__(256) void xw_kernel(
    const float* __restrict__ x, const float* __restrict__ W,
    short* __restrict__ yT)
{
  __shared__ float xs[32][129];
  __shared__ float Ws[128 * 128];
  const int t  = threadIdx.x;
  const int k0 = blockIdx.x * 32;

  #pragma unroll
  for (int i = 0; i < 16; ++i) {
    int idx = (i * 256 + t) * 4;
    *(f32x4*)&Ws[idx] = *(const f32x4*)(W + idx);
  }
  #pragma unroll
  for (int i = 0; i < 4; ++i) {
    int idx = i * 256 + t;
    int row = idx >> 5;
    int c4  = (idx & 31) * 4;
    f32x4 v = *(const f32x4*)(x + (size_t)(k0 + row) * DD + c4);
    xs[row][c4 + 0] = v[0]; xs[row][c4 + 1] = v[1];
    xs[row][c4 + 2] = v[2]; xs[row][c4 + 3] = v[3];
  }
  __syncthreads();

  const int kl = t & 31;
  const int g  = t >> 5;
  float acc[16];
  #pragma unroll
  for (int j = 0; j < 16; ++j) acc[j] = 0.f;

  for (int d = 0; d < 128; ++d) {
    float xv = xs[kl][d];
    const float* wr = &Ws[d * 128 + g * 16];
    f32x4 w0 = *(const f32x4*)(wr);
    f32x4 w1 = *(const f32x4*)(wr + 4);
    f32x4 w2 = *(const f32x4*)(wr + 8);
    f32x4 w3 = *(const f32x4*)(wr + 12);
    #pragma unroll
    for (int j = 0; j < 4; ++j) {
      acc[j]      += xv * w0[j];
      acc[4 + j]  += xv * w1[j];
      acc[8 + j]  += xv * w2[j];
      acc[12 + j] += xv * w3[j];
    }
  }
  #pragma unroll
  for (int j = 0; j < 16; ++j) {
    int n = g * 16 + j;
    yT[(size_t)n * NN + k0 + kl] = f2bf(acc[j]);
  }
}

// ===========================================================================
// A/B probe: two half-kernels, identical geometry (256 blocks, 4 waves,
// 128 rows/block, K-slice 1024, K-step 32, dbuf, same swizzle + MFMA),
// differing ONLY in the A/Y staging path:
//   gcn_dma : global_load_lds DMA  (R9 path)     rows [0, 4096)
//   gcn_reg : reg loads + ds_write (m13-ish TLP) rows [4096, 8192)
// Per-dispatch rocprof rows give the per-path read BW directly.
// ===========================================================================

// --------------------------- variant A: DMA --------------------------------
__global__ __launch_bounds__(256) void gcn_dma(
    const float* __restrict__ A, const short* __restrict__ yT,
    short* __restrict__ part, float* __restrict__ degpart)
{
  __shared__ float Abuf[2][128 * 32];   // 2 x 16 KB
  __shared__ short Ybuf[2][128 * 32];   // 2 x  8 KB

  const int tid = threadIdx.x;
  const int l   = tid & 63;
  const int w   = tid >> 6;            // wave 0..3
  const int ks  = blockIdx.x & 7;
  const int mg  = blockIdx.x >> 3;     // 0..31
  const int R0  = mg * 128;            // rows [0, 4096)
  const int kb  = ks * 1024;
  const int l31 = l & 31;
  const int hi  = l >> 5;
  const int wbase = w * 32;

  // staging sources (pre-swizzled): A instr i -> rows wbase+8i+(l>>3)
  const int a_rin  = l >> 3;
  const int a_slot = l & 7;
  const float* gA[4];
  #pragma unroll
  for (int i = 0; i < 4; ++i) {
    const int r = wbase + 8 * i + a_rin;
    gA[i] = A + (size_t)(R0 + r) * NN + kb + ((a_slot ^ (r & 7)) << 2);
  }
  // Y instr t -> rows wbase+16t+(l>>2)
  const short* gY[2];
  #pragma unroll
  for (int t = 0; t < 2; ++t) {
    const int r = wbase + 16 * t + (l >> 2);
    gY[t] = yT + (size_t)r * NN + kb + (((l & 3) ^ (r & 3)) << 3);
  }

  // read-side offsets
  const int arx = l31 & 7;
  int aoff[2][2];
  #pragma unroll
  for (int j = 0; j < 2; ++j)
    #pragma unroll
    for (int q = 0; q < 2; ++q)
      aoff[j][q] = (wbase + l31) * 32 + (((4 * j + 2 * hi + q) ^ arx) << 2);
  int yoff[4][2];
  #pragma unroll
  for (int f = 0; f < 4; ++f)
    #pragma unroll
    for (int j = 0; j < 2; ++j)
      yoff[f][j] = (f * 32 + l31) * 32 + (((2 * j + hi) ^ (l31 & 3)) << 3);

  f32x16 acc[4];
  #pragma unroll
  for (int f = 0; f < 4; ++f) acc[f] = (f32x16)0.f;
  float deg = 0.f;

#define STAGE(buf, step) do {                                           \
    const int _k = (step) * 32;                                         \
    _Pragma("unroll")                                                   \
    for (int _i = 0; _i < 4; ++_i)                                      \
      async_copy16(&Abuf[buf][(wbase + 8 * _i) * 32], gA[_i] + _k);     \
    _Pragma("unroll")                                                   \
    for (int _t = 0; _t < 2; ++_t)                                      \
      async_copy16(&Ybuf[buf][(wbase + 16 * _t) * 32], gY[_t] + _k);    \
  } while (0)

  STAGE(0, 0);
  STAGE(1, 1);

  for (int s = 0; s < 32; ++s) {
    __builtin_amdgcn_sched_barrier(0);
    if (s < 31) asm volatile("s_waitcnt vmcnt(6)" ::: "memory");
    else        asm volatile("s_waitcnt vmcnt(0)" ::: "memory");
    __builtin_amdgcn_sched_barrier(0);
    __builtin_amdgcn_s_barrier();
    __builtin_amdgcn_sched_barrier(0);

    const float* Ab = &Abuf[s & 1][0];
    const short* Yb = &Ybuf[s & 1][0];

    #pragma unroll
    for (int j = 0; j < 2; ++j) {
      f32x4 a0 = *(const f32x4*)&Ab[aoff[j][0]];
      f32x4 a1 = *(const f32x4*)&Ab[aoff[j][1]];
      deg += (a0[0] + a0[1]) + (a0[2] + a0[3])
           + (a1[0] + a1[1]) + (a1[2] + a1[3]);
      bf16x8 a;
      #pragma unroll
      for (int e = 0; e < 4; ++e) { a[e] = f2bf(a0[e]); a[4 + e] = f2bf(a1[e]); }
      #pragma unroll
      for (int f = 0; f < 4; ++f) {
        bf16x8 b = *(const bf16x8*)&Yb[yoff[f][j]];
        acc[f] = __builtin_amdgcn_mfma_f32_32x32x16_bf16(a, b, acc[f], 0, 0, 0);
      }
    }

    __builtin_amdgcn_sched_barrier(0);
    __builtin_amdgcn_s_barrier();
    __builtin_amdgcn_sched_barrier(0);
    if (s + 2 < 32) STAGE(s & 1, s + 2);
  }
#undef STAGE

  deg += __shfl_xor(deg, 32);
  if (l < 32)
    degpart[(size_t)ks * NN + R0 + wbase + l] = deg;

  short* pb = part + (size_t)ks * NN * DD + (size_t)(R0 + wbase) * DD;
  #pragma unroll
  for (int f = 0; f < 4; ++f)
    #pragma unroll
    for (int r = 0; r < 16; ++r) {
      const int row = (r & 3) + 8 * (r >> 2) + 4 * hi;
      __builtin_nontemporal_store(f2bf(acc[f][r]),
          pb + (size_t)row * DD + f * 32 + l31);
    }
}

// ------------------------ variant B: reg + ds_write ------------------------
__global__ __launch_bounds__(256) void gcn_reg(
    const float* __restrict__ A, const short* __restrict__ yT,
    short* __restrict__ part, float* __restrict__ degpart)
{
  __shared__ float Abuf[2][128 * 32];
  __shared__ short Ybuf[2][128 * 32];

  const int tid = threadIdx.x;
  const int l   = tid & 63;
  const int w   = tid >> 6;            // wave 0..3
  const int ks  = blockIdx.x & 7;
  const int mg  = blockIdx.x >> 3;
  const int R0  = 4096 + mg * 128;     // rows [4096, 8192)
  const int kb  = ks * 1024;
  const int l31 = l & 31;
  const int hi  = l >> 5;
  const int wbase = w * 32;

  // staging lane constants: lane covers row wbase+(l>>1), 64B contiguous A,
  // 32B contiguous Y (full-line coalescing across the wave)
  const int srow = wbase + (l >> 1);
  const int scol = (l & 1) * 16;       // floats (A) / shorts (Y)
  const float* gAp = A  + (size_t)(R0 + srow) * NN + kb + scol;
  const short* gYp = yT + (size_t)srow * NN + kb + scol;

  // ds_write slots (swizzled; matches read-side XOR)
  int awoff[4], ywoff[2];
  #pragma unroll
  for (int q = 0; q < 4; ++q) {
    const int g = (l & 1) * 4 + q;
    awoff[q] = srow * 32 + ((g ^ (srow & 7)) << 2);
  }
  #pragma unroll
  for (int t = 0; t < 2; ++t) {
    const int g2 = (l & 1) * 2 + t;
    ywoff[t] = srow * 32 + ((g2 ^ (srow & 3)) << 3);
  }

  // read-side offsets (identical to variant A)
  const int arx = l31 & 7;
  int aoff[2][2];
  #pragma unroll
  for (int j = 0; j < 2; ++j)
    #pragma unroll
    for (int q = 0; q < 2; ++q)
      aoff[j][q] = (wbase + l31) * 32 + (((4 * j + 2 * hi + q) ^ arx) << 2);
  int yoff[4][2];
  #pragma unroll
  for (int f = 0; f < 4; ++f)
    #pragma unroll
    for (int j = 0; j < 2; ++j)
      yoff[f][j] = (f * 32 + l31) * 32 + (((2 * j + hi) ^ (l31 & 3)) << 3);

  f32x16 acc[4];
  #pragma unroll
  for (int f = 0; f < 4; ++f) acc[f] = (f32x16)0.f;
  float deg = 0.f;

  f32x4 av0, av1, av2, av3, yv0, yv1;

#define LOADR(step) do {                                                \
    const float* _a = gAp + (step) * 32;                                \
    av0 = *(const f32x4*)(_a);      av1 = *(const f32x4*)(_a + 4);      \
    av2 = *(const f32x4*)(_a + 8);  av3 = *(const f32x4*)(_a + 12);     \
    const short* _y = gYp + (step) * 32;                                \
    yv0 = *(const f32x4*)(_y);      yv1 = *(const f32x4*)(_y + 8);      \
  } while (0)

#define WRITE(buf) do {                                                 \
    *(f32x4*)&Abuf[buf][awoff[0]] = av0;                                \
    *(f32x4*)&Abuf[buf][awoff[1]] = av1;                                \
    *(f32x4*)&Abuf[buf][awoff[2]] = av2;                                \
    *(f32x4*)&Abuf[buf][awoff[3]] = av3;                                \
    *(f32x4*)&Ybuf[buf][ywoff[0]] = yv0;                                \
    *(f32x4*)&Ybuf[buf][ywoff[1]] = yv1;                                \
  } while (0)

  // prologue: regs <- step 0; write buf0; regs <- step 1 (in flight)
  LOADR(0);
  WRITE(0);
  LOADR(1);
  asm volatile("s_waitcnt lgkmcnt(0)" ::: "memory");
  __builtin_amdgcn_sched_barrier(0);
  __builtin_amdgcn_s_barrier();

  for (int s = 0; s < 32; ++s) {
    __builtin_amdgcn_sched_barrier(0);
    const float* Ab = &Abuf[s & 1][0];
    const short* Yb = &Ybuf[s & 1][0];

    #pragma unroll
    for (int j = 0; j < 2; ++j) {
      f32x4 a0 = *(const f32x4*)&Ab[aoff[j][0]];
      f32x4 a1 = *(const f32x4*)&Ab[aoff[j][1]];
      deg += (a0[0] + a0[1]) + (a0[2] + a0[3])
           + (a1[0] + a1[1]) + (a1[2] + a1[3]);
      bf16x8 a;
      #pragma unroll
      for (int e = 0; e < 4; ++e) { a[e] = f2bf(a0[e]); a[4 + e] = f2bf(a1[e]); }
      #pragma unroll
      for (int f = 0; f < 4; ++f) {
        bf16x8 b = *(const bf16x8*)&Yb[yoff[f][j]];
        acc[f] = __builtin_amdgcn_mfma_f32_32x32x16_bf16(a, b, acc[f], 0, 0, 0);
      }
    }

    __builtin_amdgcn_sched_barrier(0);
    __builtin_amdgcn_s_barrier();     // readers done with buf[(s+1)&1]
    __builtin_amdgcn_sched_barrier(0);
    if (s + 1 < 32) {
      WRITE((s + 1) & 1);             // auto-waits vmcnt deps on regs
      __builtin_amdgcn_sched_barrier(0);
      if (s + 2 < 32) LOADR(s + 2);   // issue early: in flight across next step
      __builtin_amdgcn_sched_barrier(0);
      asm volatile("s_waitcnt lgkmcnt(0)" ::: "memory");
      __builtin_amdgcn_sched_barrier(0);
    }
    __builtin_amdgcn_s_barrier();     // writes visible
  }
#undef LOADR
#undef WRITE

  deg += __shfl_xor(deg, 32);
  if (l < 32)
    degpart[(size_t)ks * NN + R0 + wbase + l] = deg;

  short* pb = part + (size_t)ks * NN * DD + (size_t)(R0 + wbase) * DD;
  #pragma unroll
  for (int f = 0; f < 4; ++f)
    #pragma unroll
    for (int r = 0; r < 16; ++r) {
      const int row = (r & 3) + 8 * (r >> 2) + 4 * hi;
      __builtin_nontemporal_store(f2bf(acc[f][r]),
          pb + (size_t)row * DD + f * 32 + l31);
    }
}

// ---------------------------------------------------------------------------
// Kernel 3: out[m][n] = (sum_ks part[ks][m][n]) / (sum_ks degpart[ks][m])
// ---------------------------------------------------------------------------
__global__ __launch_bounds__(256) void reduce_kernel(
    const short* __restrict__ part, const float* __restrict__ degpart,
    float* __restrict__ out)
{
  const int idx = blockIdx.x * 256 + threadIdx.x;
  const int m   = idx >> 5;
  const int c4  = (idx & 31) * 4;

  float s0 = 0.f, s1 = 0.f, s2 = 0.f, s3 = 0.f, d = 0.f;
  #pragma unroll
  for (int ks = 0; ks < 8; ++ks) {
    s16x4 v = *(const s16x4*)(part + (size_t)ks * NN * DD + (size_t)m * DD + c4);
    s0 += bf2f(v[0]); s1 += bf2f(v[1]); s2 += bf2f(v[2]); s3 += bf2f(v[3]);
    d += degpart[(size_t)ks * NN + m];
  }
  f32x4 r;
  r[0] = s0 / d; r[1] = s1 / d; r[2] = s2 / d; r[3] = s3 / d;
  *(f32x4*)(out + (size_t)m * DD + c4) = r;
}

extern "C" void kernel_launch(void* const* d_in, const int* in_sizes, int n_in,
                              void* d_out, int out_size, void* d_ws, size_t ws_size,
                              hipStream_t stream) {
  const float* x = (const float*)d_in[0];   // [8192,128] fp32
  const float* A = (const float*)d_in[1];   // [8192,8192] fp32
  const float* W = (const float*)d_in[2];   // [128,128] fp32
  float* out = (float*)d_out;               // [8192,128] fp32

  char* ws = (char*)d_ws;
  short* yT      = (short*)ws;                              // 2 MB  bf16 [128][8192]
  short* part    = (short*)(ws + (2u << 20));               // 16 MB bf16 [8][8192][128]
  float* degpart = (float*)(ws + (2u << 20) + (16u << 20)); // 256 KB fp32 [8][8192]

  xw_kernel<<<256, 256, 0, stream>>>(x, W, yT);
  gcn_dma<<<256, 256, 0, stream>>>(A, yT, part, degpart);
  gcn_reg<<<256, 256, 0, stream>>>(A, yT, part, degpart);
  reduce_kernel<<<1024, 256, 0, stream>>>(part, degpart, out);
}

// Round 11
// 85.385 us; speedup vs baseline: 1.1543x; 1.1543x over previous
//
#include <hip/hip_runtime.h>
#include <hip/hip_bf16.h>

#define NN 8192
#define DD 128

typedef __attribute__((ext_vector_type(4))) float f32x4;
typedef __attribute__((ext_vector_type(16))) float f32x16;
typedef __attribute__((ext_vector_type(8))) short bf16x8;
typedef __attribute__((ext_vector_type(4))) short s16x4;

__device__ __forceinline__ short f2bf(float f) {
  __hip_bfloat16 h = __float2bfloat16(f);
  return __builtin_bit_cast(short, h);
}
__device__ __forceinline__ float bf2f(short s) {
  unsigned u = ((unsigned)(unsigned short)s) << 16;
  return __builtin_bit_cast(float, u);
}

// async global->LDS, 16B/lane. AUX = cache policy (0 = cached, 2 = NT:
// no-allocate / streaming on gfx950 CPol).
template <int AUX>
__device__ __forceinline__ void async_copy16(void* lds, const void* g) {
  __builtin_amdgcn_global_load_lds(
      (const __attribute__((address_space(1))) void*)g,
      (__attribute__((address_space(3))) void*)lds, 16, 0, AUX);
}

// ---------------------------------------------------------------------------
// Kernel 1: yT[n][k] = sum_d x[k][d] * W[d][n]   (bf16, transposed)
// ---------------------------------------------------------------------------
__global__ __launch_bounds__(256) void xw_kernel(
    const float* __restrict__ x, const float* __restrict__ W,
    short* __restrict__ yT)
{
  __shared__ float xs[32][129];
  __shared__ float Ws[128 * 128];
  const int t  = threadIdx.x;
  const int k0 = blockIdx.x * 32;

  #pragma unroll
  for (int i = 0; i < 16; ++i) {
    int idx = (i * 256 + t) * 4;
    *(f32x4*)&Ws[idx] = *(const f32x4*)(W + idx);
  }
  #pragma unroll
  for (int i = 0; i < 4; ++i) {
    int idx = i * 256 + t;
    int row = idx >> 5;
    int c4  = (idx & 31) * 4;
    f32x4 v = *(const f32x4*)(x + (size_t)(k0 + row) * DD + c4);
    xs[row][c4 + 0] = v[0]; xs[row][c4 + 1] = v[1];
    xs[row][c4 + 2] = v[2]; xs[row][c4 + 3] = v[3];
  }
  __syncthreads();

  const int kl = t & 31;
  const int g  = t >> 5;
  float acc[16];
  #pragma unroll
  for (int j = 0; j < 16; ++j) acc[j] = 0.f;

  for (int d = 0; d < 128; ++d) {
    float xv = xs[kl][d];
    const float* wr = &Ws[d * 128 + g * 16];
    f32x4 w0 = *(const f32x4*)(wr);
    f32x4 w1 = *(const f32x4*)(wr + 4);
    f32x4 w2 = *(const f32x4*)(wr + 8);
    f32x4 w3 = *(const f32x4*)(wr + 12);
    #pragma unroll
    for (int j = 0; j < 4; ++j) {
      acc[j]      += xv * w0[j];
      acc[4 + j]  += xv * w1[j];
      acc[8 + j]  += xv * w2[j];
      acc[12 + j] += xv * w3[j];
    }
  }
  #pragma unroll
  for (int j = 0; j < 16; ++j) {
    int n = g * 16 + j;
    yT[(size_t)n * NN + k0 + kl] = f2bf(acc[j]);
  }
}

// ---------------------------------------------------------------------------
// Kernel 2 == R9 structure exactly (90.9us baseline), ONE variable changed:
// A-staging cache policy ANT (0 for even 256-row bands, 2=NT for odd bands).
// Even bands (128MB) -> stable L3 residency across graph replays (~100% IC
// hit); odd bands stream from HBM with no IC allocation. Probes whether the
// IC-hit path and the HBM path serve reads concurrently (each ~3.3 TB/s) or
// share one ~3.3 TB/s request-stream cap.
// ---------------------------------------------------------------------------
template <int ANT>
__device__ __forceinline__ void gcn_body(
    const float* __restrict__ A, const short* __restrict__ yT,
    short* __restrict__ part, float* __restrict__ degpart,
    float (&Abuf)[2][256 * 32], short (&Ybuf)[2][128 * 32])
{
  const int tid = threadIdx.x;
  const int l   = tid & 63;
  const int w   = tid >> 6;            // wave 0..7
  const int ks  = blockIdx.x & 7;      // k-slice == XCD id
  const int mg  = blockIdx.x >> 3;     // 0..31
  const int R0  = mg * 256;
  const int kb  = ks * 1024;
  const int l31 = l & 31;
  const int hi  = l >> 5;
  const int wbase = w * 32;

  // staging sources (pre-swizzled)
  const int a_rin  = l >> 3;
  const int a_slot = l & 7;
  const float* gA[4];
  #pragma unroll
  for (int i = 0; i < 4; ++i) {
    const int r = wbase + 8 * i + a_rin;
    gA[i] = A + (size_t)(R0 + r) * NN + kb + ((a_slot ^ (r & 7)) << 2);
  }
  const int y_row = w * 16 + (l >> 2);
  const short* gY = yT + (size_t)y_row * NN + kb + (((l & 3) ^ (y_row & 3)) << 3);

  // read-side offsets
  const int arx = l31 & 7;
  int aoff[2][2];
  #pragma unroll
  for (int j = 0; j < 2; ++j)
    #pragma unroll
    for (int q = 0; q < 2; ++q)
      aoff[j][q] = (wbase + l31) * 32 + (((4 * j + 2 * hi + q) ^ arx) << 2);
  int yoff[4][2];
  #pragma unroll
  for (int f = 0; f < 4; ++f)
    #pragma unroll
    for (int j = 0; j < 2; ++j)
      yoff[f][j] = (f * 32 + l31) * 32 + (((2 * j + hi) ^ (l31 & 3)) << 3);

  f32x16 acc[4];
  #pragma unroll
  for (int f = 0; f < 4; ++f) acc[f] = (f32x16)0.f;
  float deg = 0.f;

#define STAGE(buf, step) do {                                              \
    const int _k = (step) * 32;                                            \
    _Pragma("unroll")                                                      \
    for (int _i = 0; _i < 4; ++_i)                                         \
      async_copy16<ANT>(&Abuf[buf][(wbase + 8 * _i) * 32], gA[_i] + _k);   \
    async_copy16<0>(&Ybuf[buf][w * 512], gY + _k);                         \
  } while (0)

  STAGE(0, 0);
  STAGE(1, 1);

  for (int s = 0; s < 32; ++s) {
    __builtin_amdgcn_sched_barrier(0);
    if (s < 31) asm volatile("s_waitcnt vmcnt(5)" ::: "memory");
    else        asm volatile("s_waitcnt vmcnt(0)" ::: "memory");
    __builtin_amdgcn_sched_barrier(0);
    __builtin_amdgcn_s_barrier();
    __builtin_amdgcn_sched_barrier(0);

    const float* Ab = &Abuf[s & 1][0];
    const short* Yb = &Ybuf[s & 1][0];

    #pragma unroll
    for (int j = 0; j < 2; ++j) {
      f32x4 a0 = *(const f32x4*)&Ab[aoff[j][0]];
      f32x4 a1 = *(const f32x4*)&Ab[aoff[j][1]];

      deg += (a0[0] + a0[1]) + (a0[2] + a0[3])
           + (a1[0] + a1[1]) + (a1[2] + a1[3]);

      bf16x8 a;
      #pragma unroll
      for (int e = 0; e < 4; ++e) { a[e] = f2bf(a0[e]); a[4 + e] = f2bf(a1[e]); }

      #pragma unroll
      for (int f = 0; f < 4; ++f) {
        bf16x8 b = *(const bf16x8*)&Yb[yoff[f][j]];
        acc[f] = __builtin_amdgcn_mfma_f32_32x32x16_bf16(a, b, acc[f], 0, 0, 0);
      }
    }

    __builtin_amdgcn_sched_barrier(0);
    __builtin_amdgcn_s_barrier();
    __builtin_amdgcn_sched_barrier(0);
    if (s + 2 < 32) STAGE(s & 1, s + 2);
  }
#undef STAGE

  deg += __shfl_xor(deg, 32);
  if (l < 32)
    degpart[(size_t)ks * NN + R0 + wbase + l] = deg;

  short* pb = part + (size_t)ks * NN * DD + (size_t)(R0 + wbase) * DD;
  #pragma unroll
  for (int f = 0; f < 4; ++f)
    #pragma unroll
    for (int r = 0; r < 16; ++r) {
      const int row = (r & 3) + 8 * (r >> 2) + 4 * hi;
      __builtin_nontemporal_store(f2bf(acc[f][r]),
          pb + (size_t)row * DD + f * 32 + l31);
    }
}

__global__ __launch_bounds__(512, 4) void gcn_main(
    const float* __restrict__ A, const short* __restrict__ yT,
    short* __restrict__ part, float* __restrict__ degpart)
{
  __shared__ float Abuf[2][256 * 32];   // 2 x 32 KB
  __shared__ short Ybuf[2][128 * 32];   // 2 x  8 KB
  const int mg = blockIdx.x >> 3;
  if (mg & 1) gcn_body<2>(A, yT, part, degpart, Abuf, Ybuf);  // NT (stream)
  else        gcn_body<0>(A, yT, part, degpart, Abuf, Ybuf);  // cached (pin)
}

// ---------------------------------------------------------------------------
// Kernel 3: out[m][n] = (sum_ks part[ks][m][n]) / (sum_ks degpart[ks][m])
// ---------------------------------------------------------------------------
__global__ __launch_bounds__(256) void reduce_kernel(
    const short* __restrict__ part, const float* __restrict__ degpart,
    float* __restrict__ out)
{
  const int idx = blockIdx.x * 256 + threadIdx.x;
  const int m   = idx >> 5;
  const int c4  = (idx & 31) * 4;

  float s0 = 0.f, s1 = 0.f, s2 = 0.f, s3 = 0.f, d = 0.f;
  #pragma unroll
  for (int ks = 0; ks < 8; ++ks) {
    s16x4 v = *(const s16x4*)(part + (size_t)ks * NN * DD + (size_t)m * DD + c4);
    s0 += bf2f(v[0]); s1 += bf2f(v[1]); s2 += bf2f(v[2]); s3 += bf2f(v[3]);
    d += degpart[(size_t)ks * NN + m];
  }
  f32x4 r;
  r[0] = s0 / d; r[1] = s1 / d; r[2] = s2 / d; r[3] = s3 / d;
  *(f32x4*)(out + (size_t)m * DD + c4) = r;
}

extern "C" void kernel_launch(void* const* d_in, const int* in_sizes, int n_in,
                              void* d_out, int out_size, void* d_ws, size_t ws_size,
                              hipStream_t stream) {
  const float* x = (const float*)d_in[0];   // [8192,128] fp32
  const float* A = (const float*)d_in[1];   // [8192,8192] fp32
  const float* W = (const float*)d_in[2];   // [128,128] fp32
  float* out = (float*)d_out;               // [8192,128] fp32

  char* ws = (char*)d_ws;
  short* yT      = (short*)ws;                              // 2 MB  bf16 [128][8192]
  short* part    = (short*)(ws + (2u << 20));               // 16 MB bf16 [8][8192][128]
  float* degpart = (float*)(ws + (2u << 20) + (16u << 20)); // 256 KB fp32 [8][8192]

  xw_kernel<<<256, 256, 0, stream>>>(x, W, yT);
  gcn_main<<<256, 512, 0, stream>>>(A, yT, part, degpart);
  reduce_kernel<<<1024, 256, 0, stream>>>(part, degpart, out);
}